// Round 1
// baseline (22170.769 us; speedup 1.0000x reference)
//
#include <hip/hip_runtime.h>
#include <math.h>

// RNN: 4 layers, H=2048, T=512, tanh, then FC on last timestep.
// Strategy: ONE persistent kernel, 128 blocks x 512 threads.
//  - Each block owns 16 rows of h. Per lane: 4 rows x 16 cols of BOTH
//    W_ih and W_hh held in VGPRs (128 weight regs/lane).
//  - Per timestep: poll per-block flags (LLC-coherent), load h_{t-1} (own
//    layer) + h_prev_layer[t] (or x column for layer 0), 128 FMAs, wave
//    butterfly reduce, wave-pair combine via LDS, tanh, store 16 h values,
//    release-store monotonic flag.
//  - Layers run sequentially (flag threshold l*T+t orders everything).
//  - Final FC matvec after flags reach 4*T.
// All cross-block traffic uses __hip_atomic_* AGENT scope (per-XCD L2s are
// not coherent on MI355X).

#define HH 2048
#define TT 512
#define NL 4
#define NB 128
#define NTH 512

__device__ __forceinline__ float2 ld_coh2(const float* p) {
  unsigned long long v = __hip_atomic_load((const unsigned long long*)p,
                                           __ATOMIC_RELAXED,
                                           __HIP_MEMORY_SCOPE_AGENT);
  float2 r;
  r.x = __uint_as_float((unsigned int)(v & 0xffffffffULL));
  r.y = __uint_as_float((unsigned int)(v >> 32));
  return r;
}

__launch_bounds__(NTH, 2)
__global__ void rnn_persist(const float* __restrict__ x,
                            const float* __restrict__ w_ih,
                            const float* __restrict__ w_hh,
                            const float* __restrict__ b_ih,
                            const float* __restrict__ b_hh,
                            const float* __restrict__ w_fc,
                            const float* __restrict__ b_fc,
                            float* __restrict__ out,
                            float* ws)
{
  const int blk  = blockIdx.x;
  const int tid  = threadIdx.x;
  const int wid  = tid >> 6;
  const int lane = tid & 63;
  const int band = wid >> 1;                 // 4 bands of 4 rows
  const int half = wid & 1;                  // col half (0..1023 / 1024..2047)
  const int rowbase = blk * 16 + band * 4;
  const int colbase = half * 1024 + lane * 16;

  float* buf0 = ws;                                    // (TT+1) x HH
  float* buf1 = ws + (size_t)(TT + 1) * HH;            // (TT+1) x HH
  int*  flags = (int*)(ws + (size_t)2 * (TT + 1) * HH);
  unsigned long long* flags64 = (unsigned long long*)flags;

  __shared__ float partial[8][4];

  for (int l = 0; l < NL; ++l) {
    float* bout       = (l & 1) ? buf1 : buf0;
    const float* binp = (l & 1) ? buf0 : buf1;   // unused for l==0

    // ---- load this layer's weight slice into registers ----
    float wih[4][16], whh[4][16];
#pragma unroll
    for (int r = 0; r < 4; ++r) {
      const float* pih = w_ih + ((size_t)l * HH + (rowbase + r)) * HH + colbase;
      const float* phh = w_hh + ((size_t)l * HH + (rowbase + r)) * HH + colbase;
#pragma unroll
      for (int k = 0; k < 16; ++k) { wih[r][k] = pih[k]; whh[r][k] = phh[k]; }
    }
    float fbias = 0.f;
    if (tid < 16) {
      int row = blk * 16 + tid;
      fbias = b_ih[l * HH + row] + b_hh[l * HH + row];
    }

    for (int t = 0; t < TT; ++t) {
      const int need = l * TT + t;   // all blocks must have published `need`
      if (need > 0) {
        for (;;) {
          unsigned long long ff = __hip_atomic_load(flags64 + lane,
                                                    __ATOMIC_RELAXED,
                                                    __HIP_MEMORY_SCOPE_AGENT);
          int ok = ((int)(ff & 0xffffffffULL) >= need) &&
                   ((int)(ff >> 32) >= need);
          if (__all(ok)) break;
          __builtin_amdgcn_s_sleep(1);
        }
      }

      // h_{t-1} of own layer (slot t; slot 0 pre-zeroed)
      float hh[16], hi[16];
      {
        const float* ph = bout + (size_t)t * HH + colbase;
#pragma unroll
        for (int k = 0; k < 8; ++k) {
          float2 v = ld_coh2(ph + 2 * k);
          hh[2 * k] = v.x; hh[2 * k + 1] = v.y;
        }
      }
      // input at time t: x column (layer 0) or previous layer's h[t]
      if (l == 0) {
#pragma unroll
        for (int k = 0; k < 16; ++k)
          hi[k] = x[(size_t)(colbase + k) * TT + t];
      } else {
        const float* ph = binp + (size_t)(t + 1) * HH + colbase;
#pragma unroll
        for (int k = 0; k < 8; ++k) {
          float2 v = ld_coh2(ph + 2 * k);
          hi[2 * k] = v.x; hi[2 * k + 1] = v.y;
        }
      }

      float a0 = 0.f, a1 = 0.f, a2 = 0.f, a3 = 0.f;
#pragma unroll
      for (int k = 0; k < 16; ++k) {
        a0 += whh[0][k] * hh[k]; a0 += wih[0][k] * hi[k];
        a1 += whh[1][k] * hh[k]; a1 += wih[1][k] * hi[k];
        a2 += whh[2][k] * hh[k]; a2 += wih[2][k] * hi[k];
        a3 += whh[3][k] * hh[k]; a3 += wih[3][k] * hi[k];
      }
      // butterfly reduce across the 64 lanes (4 rows packed)
#pragma unroll
      for (int m = 1; m < 64; m <<= 1) {
        a0 += __shfl_xor(a0, m, 64);
        a1 += __shfl_xor(a1, m, 64);
        a2 += __shfl_xor(a2, m, 64);
        a3 += __shfl_xor(a3, m, 64);
      }
      if (lane == 0) {
        partial[wid][0] = a0; partial[wid][1] = a1;
        partial[wid][2] = a2; partial[wid][3] = a3;
      }
      __syncthreads();
      if (tid < 16) {                       // all finalizers live in wave 0
        int bnd = tid >> 2, r = tid & 3;
        float s = partial[bnd * 2][r] + partial[bnd * 2 + 1][r] + fbias;
        float hv = tanhf(s);
        __hip_atomic_store(bout + (size_t)(t + 1) * HH + blk * 16 + tid, hv,
                           __ATOMIC_RELAXED, __HIP_MEMORY_SCOPE_AGENT);
      }
      if (tid == 0) {                       // release orders wave-0's stores
        __hip_atomic_store(flags + blk, need + 1,
                           __ATOMIC_RELEASE, __HIP_MEMORY_SCOPE_AGENT);
      }
      // no trailing barrier needed: waves re-enter poll, which is gated by
      // our own flag (set only after wave 0 consumed the LDS partials).
    }
  }

  // ---- final FC on h_seq[-1] (layer 3 output lives in buf1 slot TT) ----
  {
    const int need = NL * TT;
    for (;;) {
      unsigned long long ff = __hip_atomic_load(flags64 + lane,
                                                __ATOMIC_RELAXED,
                                                __HIP_MEMORY_SCOPE_AGENT);
      int ok = ((int)(ff & 0xffffffffULL) >= need) &&
               ((int)(ff >> 32) >= need);
      if (__all(ok)) break;
      __builtin_amdgcn_s_sleep(1);
    }

    float wf[4][16];
#pragma unroll
    for (int r = 0; r < 4; ++r) {
      const float* pf = w_fc + (size_t)(rowbase + r) * HH + colbase;
#pragma unroll
      for (int k = 0; k < 16; ++k) wf[r][k] = pf[k];
    }
    float hv[16];
    const float* ph = buf1 + (size_t)TT * HH + colbase;
#pragma unroll
    for (int k = 0; k < 8; ++k) {
      float2 v = ld_coh2(ph + 2 * k);
      hv[2 * k] = v.x; hv[2 * k + 1] = v.y;
    }
    float a0 = 0.f, a1 = 0.f, a2 = 0.f, a3 = 0.f;
#pragma unroll
    for (int k = 0; k < 16; ++k) {
      a0 += wf[0][k] * hv[k];
      a1 += wf[1][k] * hv[k];
      a2 += wf[2][k] * hv[k];
      a3 += wf[3][k] * hv[k];
    }
#pragma unroll
    for (int m = 1; m < 64; m <<= 1) {
      a0 += __shfl_xor(a0, m, 64);
      a1 += __shfl_xor(a1, m, 64);
      a2 += __shfl_xor(a2, m, 64);
      a3 += __shfl_xor(a3, m, 64);
    }
    if (lane == 0) {
      partial[wid][0] = a0; partial[wid][1] = a1;
      partial[wid][2] = a2; partial[wid][3] = a3;
    }
    __syncthreads();
    if (tid < 16) {
      int row = blk * 16 + tid;
      int bnd = tid >> 2, r = tid & 3;
      out[row] = partial[bnd * 2][r] + partial[bnd * 2 + 1][r] + b_fc[row];
    }
  }
}

extern "C" void kernel_launch(void* const* d_in, const int* in_sizes, int n_in,
                              void* d_out, int out_size, void* d_ws, size_t ws_size,
                              hipStream_t stream) {
  const float* x    = (const float*)d_in[0];
  const float* w_ih = (const float*)d_in[1];
  const float* w_hh = (const float*)d_in[2];
  const float* b_ih = (const float*)d_in[3];
  const float* b_hh = (const float*)d_in[4];
  const float* w_fc = (const float*)d_in[5];
  const float* b_fc = (const float*)d_in[6];
  float* out = (float*)d_out;
  float* ws  = (float*)d_ws;

  float* buf0 = ws;
  float* buf1 = ws + (size_t)(TT + 1) * HH;
  int*  flags = (int*)(ws + (size_t)2 * (TT + 1) * HH);

  // zero the h_{-1} slots and the progress flags (fresh every launch/replay)
  hipMemsetAsync(buf0, 0, HH * sizeof(float), stream);
  hipMemsetAsync(buf1, 0, HH * sizeof(float), stream);
  hipMemsetAsync(flags, 0, NB * sizeof(int), stream);

  rnn_persist<<<NB, NTH, 0, stream>>>(x, w_ih, w_hh, b_ih, b_hh,
                                      w_fc, b_fc, out, ws);
}

// Round 2
// 6315.728 us; speedup vs baseline: 3.5104x; 3.5104x over previous
//
#include <hip/hip_runtime.h>
#include <math.h>

// 4-layer tanh RNN (H=2048, T=512) + FC on last timestep.
// Round-2 design:
//  - Persistent kernel, 256 blocks x 512 threads (1 block/CU guaranteed by
//    __launch_bounds__(512,2): 8 waves @ <=256 VGPR -> exactly 2 waves/SIMD).
//  - Depth-2 layer pipeline: blocks 0..127 (group A) run layer 0 then layer 2;
//    blocks 128..255 (group B) run layer 1 then layer 3 (each trails its
//    producer layer by ~1 step). Critical path ~2*(T+1) steps instead of 4*T.
//  - Handshake = DATA-AS-FLAG: exchange buffers pre-filled with 0xFFFFFFFF
//    (a NaN tanh can never produce; slot 0 zeroed = h_{-1}). Consumers poll
//    the data itself with agent-scope 8B atomic loads -> detection and fetch
//    are the same MALL round trip; no flags, no fences.
//  - Cooperative polling: each wave polls only its 1/8 slice of h (and of the
//    prev-layer vector), lane-contiguous (coalesced 512B per instruction),
//    deposits to LDS, __syncthreads, then lanes read their interleaved
//    column set (c = half*1024 + 128k + 2*lane; 8B LDS reads, conflict-free).
//  - Per lane: 4 rows x 16 cols of W_ih and W_hh in VGPRs (128 regs), fp32.

#define HH 2048
#define TT 512
#define NB 256
#define GRPB 128
#define NTH 512

typedef unsigned long long u64;
typedef unsigned int u32;

__device__ __forceinline__ u64 ld_a8(const float* p) {
  return __hip_atomic_load((const u64*)p, __ATOMIC_RELAXED,
                           __HIP_MEMORY_SCOPE_AGENT);
}
__device__ __forceinline__ void st_a4(float* p, float v) {
  __hip_atomic_store(p, v, __ATOMIC_RELAXED, __HIP_MEMORY_SCOPE_AGENT);
}
__device__ __forceinline__ bool fresh8(u64 v) {
  return ((u32)v != 0xFFFFFFFFu) & ((u32)(v >> 32) != 0xFFFFFFFFu);
}

__launch_bounds__(NTH, 2)
__global__ void rnn_pipe(const float* __restrict__ x,
                         const float* __restrict__ w_ih,
                         const float* __restrict__ w_hh,
                         const float* __restrict__ b_ih,
                         const float* __restrict__ b_hh,
                         const float* __restrict__ w_fc,
                         const float* __restrict__ b_fc,
                         float* __restrict__ out,
                         float* ws)
{
  const int blk  = blockIdx.x;
  const bool gA  = (blk < GRPB);
  const int gb   = gA ? blk : (blk - GRPB);
  const int tid  = threadIdx.x;
  const int wid  = tid >> 6;
  const int lane = tid & 63;
  const int band = wid >> 1;      // 4 bands of 4 rows
  const int half = wid & 1;       // column half
  const int rowbase = gb * 16 + band * 4;

  __shared__ float hex_own[HH];    // h_{t-1}, own layer
  __shared__ float hex_prev[HH];   // h_t, previous layer
  __shared__ float partial[8][4];

  // cooperative poll slice: wave w owns cols [w*256, w*256+256); 4 floats/lane
  const int sl = wid * 256 + lane * 4;

  for (int phase = 0; phase < 2; ++phase) {
    const int l = (phase == 0) ? (gA ? 0 : 1) : (gA ? 2 : 3);
    float* outB      = ws + (size_t)l * (TT + 1) * HH;
    const float* inB = (l == 0) ? (const float*)0
                                : ws + (size_t)(l - 1) * (TT + 1) * HH;

    // ---- weights into VGPRs: lane owns cols c(k)=half*1024+128k+2*lane ----
    float wih[4][16], whh[4][16];
#pragma unroll
    for (int r = 0; r < 4; ++r) {
      const float* pih = w_ih + ((size_t)l * HH + rowbase + r) * HH;
      const float* phh = w_hh + ((size_t)l * HH + rowbase + r) * HH;
#pragma unroll
      for (int k = 0; k < 8; ++k) {
        int c = half * 1024 + k * 128 + lane * 2;
        float2 a = *(const float2*)(pih + c);
        float2 b = *(const float2*)(phh + c);
        wih[r][2 * k] = a.x; wih[r][2 * k + 1] = a.y;
        whh[r][2 * k] = b.x; whh[r][2 * k + 1] = b.y;
      }
    }
    float fbias = 0.f;
    if (tid < 16)
      fbias = b_ih[l * HH + gb * 16 + tid] + b_hh[l * HH + gb * 16 + tid];

    for (int t = 0; t < TT; ++t) {
      // ---- cooperative sentinel poll + fetch (own slot t, prev slot t+1) ---
      const float* po = outB + (size_t)t * HH + sl;
      const float* pp = (l > 0) ? (inB + (size_t)(t + 1) * HH + sl)
                                : (const float*)0;
      u64 o0, o1, p0 = 0, p1 = 0;
      for (;;) {
        o0 = ld_a8(po);
        o1 = ld_a8(po + 2);
        if (l > 0) { p0 = ld_a8(pp); p1 = ld_a8(pp + 2); }
        bool ok = fresh8(o0) & fresh8(o1);
        if (l > 0) ok = ok & fresh8(p0) & fresh8(p1);
        if (__all(ok)) break;
        __builtin_amdgcn_s_sleep(2);
      }
      *(u64*)(hex_own + sl)     = o0;
      *(u64*)(hex_own + sl + 2) = o1;
      if (l > 0) {
        *(u64*)(hex_prev + sl)     = p0;
        *(u64*)(hex_prev + sl + 2) = p1;
      }
      __syncthreads();   // barrier1: hexch ready

      float hh[16], hi[16];
#pragma unroll
      for (int k = 0; k < 8; ++k) {
        int c = half * 1024 + k * 128 + lane * 2;
        float2 v = *(const float2*)(hex_own + c);
        hh[2 * k] = v.x; hh[2 * k + 1] = v.y;
      }
      if (l == 0) {
#pragma unroll
        for (int k = 0; k < 8; ++k) {
          int c = half * 1024 + k * 128 + lane * 2;
          hi[2 * k]     = x[(size_t)c * TT + t];
          hi[2 * k + 1] = x[(size_t)(c + 1) * TT + t];
        }
      } else {
#pragma unroll
        for (int k = 0; k < 8; ++k) {
          int c = half * 1024 + k * 128 + lane * 2;
          float2 v = *(const float2*)(hex_prev + c);
          hi[2 * k] = v.x; hi[2 * k + 1] = v.y;
        }
      }

      float a0 = 0.f, a1 = 0.f, a2 = 0.f, a3 = 0.f;
#pragma unroll
      for (int k = 0; k < 16; ++k) {
        a0 += whh[0][k] * hh[k]; a0 += wih[0][k] * hi[k];
        a1 += whh[1][k] * hh[k]; a1 += wih[1][k] * hi[k];
        a2 += whh[2][k] * hh[k]; a2 += wih[2][k] * hi[k];
        a3 += whh[3][k] * hh[k]; a3 += wih[3][k] * hi[k];
      }
#pragma unroll
      for (int m = 1; m < 64; m <<= 1) {
        a0 += __shfl_xor(a0, m, 64);
        a1 += __shfl_xor(a1, m, 64);
        a2 += __shfl_xor(a2, m, 64);
        a3 += __shfl_xor(a3, m, 64);
      }
      if (lane == 0) {
        partial[wid][0] = a0; partial[wid][1] = a1;
        partial[wid][2] = a2; partial[wid][3] = a3;
      }
      __syncthreads();   // barrier2: partials ready
      if (tid < 16) {
        int bnd = tid >> 2, r = tid & 3;
        float s = partial[bnd * 2][r] + partial[bnd * 2 + 1][r] + fbias;
        st_a4(outB + (size_t)(t + 1) * HH + gb * 16 + tid, tanhf(s));
      }
      // next step's poll is gated (via MALL round trip) on our wave-0 store,
      // so LDS reuse at t+1 cannot race wave 0's finalize of step t.
    }
    __syncthreads();   // phase boundary
  }

  // ---- FC on h3[T-1] (group A only; 16 output rows per block) ----
  if (gA) {
    const float* bufL3 = ws + (size_t)3 * (TT + 1) * HH;
    float wf[4][16];
#pragma unroll
    for (int r = 0; r < 4; ++r) {
      const float* pf = w_fc + (size_t)(rowbase + r) * HH;
#pragma unroll
      for (int k = 0; k < 8; ++k) {
        int c = half * 1024 + k * 128 + lane * 2;
        float2 a = *(const float2*)(pf + c);
        wf[r][2 * k] = a.x; wf[r][2 * k + 1] = a.y;
      }
    }
    const float* ph = bufL3 + (size_t)TT * HH + sl;
    u64 o0, o1;
    for (;;) {
      o0 = ld_a8(ph);
      o1 = ld_a8(ph + 2);
      if (__all(fresh8(o0) & fresh8(o1))) break;
      __builtin_amdgcn_s_sleep(2);
    }
    *(u64*)(hex_own + sl)     = o0;
    *(u64*)(hex_own + sl + 2) = o1;
    __syncthreads();

    float hv[16];
#pragma unroll
    for (int k = 0; k < 8; ++k) {
      int c = half * 1024 + k * 128 + lane * 2;
      float2 v = *(const float2*)(hex_own + c);
      hv[2 * k] = v.x; hv[2 * k + 1] = v.y;
    }
    float a0 = 0.f, a1 = 0.f, a2 = 0.f, a3 = 0.f;
#pragma unroll
    for (int k = 0; k < 16; ++k) {
      a0 += wf[0][k] * hv[k];
      a1 += wf[1][k] * hv[k];
      a2 += wf[2][k] * hv[k];
      a3 += wf[3][k] * hv[k];
    }
#pragma unroll
    for (int m = 1; m < 64; m <<= 1) {
      a0 += __shfl_xor(a0, m, 64);
      a1 += __shfl_xor(a1, m, 64);
      a2 += __shfl_xor(a2, m, 64);
      a3 += __shfl_xor(a3, m, 64);
    }
    if (lane == 0) {
      partial[wid][0] = a0; partial[wid][1] = a1;
      partial[wid][2] = a2; partial[wid][3] = a3;
    }
    __syncthreads();
    if (tid < 16) {
      int row = gb * 16 + tid;
      int bnd = tid >> 2, r = tid & 3;
      out[row] = partial[bnd * 2][r] + partial[bnd * 2 + 1][r] + b_fc[row];
    }
  }
}

extern "C" void kernel_launch(void* const* d_in, const int* in_sizes, int n_in,
                              void* d_out, int out_size, void* d_ws, size_t ws_size,
                              hipStream_t stream) {
  const float* x    = (const float*)d_in[0];
  const float* w_ih = (const float*)d_in[1];
  const float* w_hh = (const float*)d_in[2];
  const float* b_ih = (const float*)d_in[3];
  const float* b_hh = (const float*)d_in[4];
  const float* w_fc = (const float*)d_in[5];
  const float* b_fc = (const float*)d_in[6];
  float* out = (float*)d_out;
  float* ws  = (float*)d_ws;

  // 4 exchange buffers, one per layer: (TT+1) x HH floats each.
  // Sentinel-fill all of them, then zero slot 0 (= h_{-1}) of each.
  const size_t bufFloats = (size_t)(TT + 1) * HH;
  hipMemsetAsync(ws, 0xFF, 4 * bufFloats * sizeof(float), stream);
  for (int l = 0; l < 4; ++l)
    hipMemsetAsync(ws + l * bufFloats, 0, HH * sizeof(float), stream);

  rnn_pipe<<<NB, NTH, 0, stream>>>(x, w_ih, w_hh, b_ih, b_hh,
                                   w_fc, b_fc, out, ws);
}